// Round 7
// baseline (306.864 us; speedup 1.0000x reference)
//
#include <hip/hip_runtime.h>
#include <hip/hip_bf16.h>
#include <math.h>

#define B_ 4
#define S_ 2048
#define D_ 768
#define H_ 12
#define HD_ 64
#define P_ 768
#define M_ (B_*S_)   // 8192
#define NCH 32       // chunks per sequence
#define CH 64        // chunk length
#define BH (B_*H_)   // 48

typedef __hip_bfloat16 bf16;
typedef __attribute__((ext_vector_type(8))) short short8;
typedef __attribute__((ext_vector_type(4))) short s16x4;
typedef __attribute__((ext_vector_type(4))) float f32x4;

__device__ __forceinline__ float wave_reduce_sum(float v){
  #pragma unroll
  for (int off=32; off>0; off>>=1) v += __shfl_xor(v, off, 64);
  return v;
}
__device__ __forceinline__ float bf2f(bf16 h){ return __bfloat162float(h); }
__device__ __forceinline__ float us2f(unsigned short u){
  union{unsigned int i; float f;} z; z.i = ((unsigned int)u)<<16; return z.f;
}
// swizzled LDS [64][64] bf16 tiles (128B rows): byte ^= (row&7)<<4
__device__ __forceinline__ int adr(int row, int col){ return (row*128 + col*2) ^ ((row&7)<<4); }
__device__ __forceinline__ short8 lfrag(const char* base, int row, int col){
  return *(const short8*)(base + adr(row,col));
}
__device__ __forceinline__ short8 gfrag(const bf16* g, int row, int col){
  return *(const short8*)(g + row*64 + col);
}
__device__ __forceinline__ f32x4 MM(short8 a, short8 b, f32x4 c){
  return __builtin_amdgcn_mfma_f32_16x16x32_bf16(a, b, c, 0,0,0);
}
__device__ __forceinline__ short f2s(float v){ bf16 h = __float2bfloat16(v); return *(short*)&h; }
// packed C^T store: lane's 4 values C[m0..m0+3][n] -> tile[n][m0..m0+3]
__device__ __forceinline__ void stpk(char* b, int n, int m0, float v0,float v1,float v2,float v3){
  s16x4 p = { f2s(v0), f2s(v1), f2s(v2), f2s(v3) };
  *(s16x4*)(b + adr(n, m0)) = p;
}
__device__ __forceinline__ void stpk_hl(char* bh, char* bl, int n, int m0,
                                        float v0,float v1,float v2,float v3){
  float h0=bf2f(__float2bfloat16(v0)), h1=bf2f(__float2bfloat16(v1));
  float h2=bf2f(__float2bfloat16(v2)), h3=bf2f(__float2bfloat16(v3));
  stpk(bh, n, m0, h0,h1,h2,h3);
  stpk(bl, n, m0, v0-h0, v1-h1, v2-h2, v3-h3);
}
__device__ __forceinline__ float4 ldpk2(const char* bh, const char* bl, int n, int m0){
  s16x4 a = *(const s16x4*)(bh + adr(n,m0));
  s16x4 b = *(const s16x4*)(bl + adr(n,m0));
  return make_float4(us2f((unsigned short)a[0])+us2f((unsigned short)b[0]),
                     us2f((unsigned short)a[1])+us2f((unsigned short)b[1]),
                     us2f((unsigned short)a[2])+us2f((unsigned short)b[2]),
                     us2f((unsigned short)a[3])+us2f((unsigned short)b[3]));
}
// async global->LDS, 16B per lane, LDS dest = wave-uniform base + lane*16
__device__ __forceinline__ void gl_lds(const bf16* g, const bf16* l){
  __builtin_amdgcn_global_load_lds(
      (const __attribute__((address_space(1))) void*)g,
      (__attribute__((address_space(3))) void*)l, 16, 0, 0);
}

// ---------------- merged weight/bias packing ----------------
__global__ __launch_bounds__(256) void pack_all_kernel(
    const float* __restrict__ km1,const float* __restrict__ vm1,const float* __restrict__ qm1,
    const float* __restrict__ Wk,const float* __restrict__ Wv,const float* __restrict__ Wq,
    const float* __restrict__ k2,const float* __restrict__ v2,const float* __restrict__ q2,
    const float* __restrict__ Wo,const float* __restrict__ Wg,
    const float* __restrict__ kb1,const float* __restrict__ vb1,const float* __restrict__ qb1,
    const float* __restrict__ kb2,const float* __restrict__ vb2,const float* __restrict__ qb2,
    const float* __restrict__ lnkg,const float* __restrict__ lnvg,const float* __restrict__ lnqg,
    const float* __restrict__ lnkb,const float* __restrict__ lnvb,const float* __restrict__ lnqb,
    bf16* __restrict__ Whb, bf16* __restrict__ Wkvqb, bf16* __restrict__ Wob,
    bf16* __restrict__ Wgb, float* __restrict__ biasb)
{
  int i = blockIdx.x*256 + threadIdx.x;
  if (i < 491520){                       // Wh pad 640x768
    int r = i/768, c = i%768;
    float v = 0.f;
    if (r < 192) v = km1[r*768+c];
    else if (r < 384) v = vm1[(r-192)*768+c];
    else if (r < 576) v = qm1[(r-384)*768+c];
    Whb[i] = __float2bfloat16(v);
  } else if (i < 2703360){               // Wkvq 2304x960
    int i2 = i - 491520;
    int r = i2/960, c = i2%960;
    int p = r/768, rr = r%768;
    const float* W  = (p==0)?Wk:(p==1)?Wv:Wq;
    const float* w2 = (p==0)?k2:(p==1)?v2:q2;
    float v = (c < 768) ? W[(size_t)rr*768+c] : 0.1f*w2[(size_t)rr*192 + (c-768)];
    Wkvqb[i2] = __float2bfloat16(v);
  } else if (i < 3293184){
    int i2 = i - 2703360;
    Wob[i2] = __float2bfloat16(Wo[i2]);
  } else if (i < 3883008){
    int i2 = i - 3293184;
    Wgb[i2] = __float2bfloat16(Wg[i2]);
  } else if (i < 3886272){
    int i2 = i - 3883008;                // 3264 floats
    if (i2 < 576){
      biasb[i2] = (i2<192)? kb1[i2] : (i2<384)? vb1[i2-192] : qb1[i2-384];
    } else if (i2 < 2880){
      int r = i2-576; int p = r/768, rr = r%768;
      const float* b2 = (p==0)?kb2:(p==1)?vb2:qb2;
      biasb[i2] = 0.1f*b2[rr];
    } else if (i2 < 3072){
      int k3 = i2-2880; int gg=k3/64, cc=k3%64;
      biasb[i2] = (gg==0?lnkg:gg==1?lnvg:lnqg)[cc];
    } else {
      int k3 = i2-3072; int gg=k3/64, cc=k3%64;
      biasb[i2] = (gg==0?lnkb:gg==1?lnvb:lnqb)[cc];
    }
  }
}

// ---------------- input layernorm ----------------
__global__ __launch_bounds__(256) void ln_in_kernel(const float* __restrict__ x, const float* __restrict__ g,
                                                    const float* __restrict__ bta,
                                                    bf16* __restrict__ xn, bf16* __restrict__ xb){
  int row = blockIdx.x;
  const float* xr = x + (size_t)row*D_;
  int t = threadIdx.x;
  float v0 = xr[t], v1 = xr[t+256], v2 = xr[t+512];
  float s  = v0+v1+v2;
  float sq = v0*v0+v1*v1+v2*v2;
  s = wave_reduce_sum(s); sq = wave_reduce_sum(sq);
  __shared__ float red[8];
  int w = t>>6;
  if ((t&63)==0){ red[w]=s; red[4+w]=sq; }
  __syncthreads();
  s  = red[0]+red[1]+red[2]+red[3];
  sq = red[4]+red[5]+red[6]+red[7];
  float mean = s*(1.f/D_);
  float var  = sq*(1.f/D_) - mean*mean;
  float inv  = rsqrtf(var + 1e-5f);
  bf16* xnr = xn + (size_t)row*D_;
  bf16* xbr = xb + (size_t)row*D_;
  xnr[t]     = __float2bfloat16((v0-mean)*inv*g[t]     + bta[t]);
  xnr[t+256] = __float2bfloat16((v1-mean)*inv*g[t+256] + bta[t+256]);
  xnr[t+512] = __float2bfloat16((v2-mean)*inv*g[t+512] + bta[t+512]);
  xbr[t] = __float2bfloat16(v0); xbr[t+256] = __float2bfloat16(v1); xbr[t+512] = __float2bfloat16(v2);
}

// ---------------- GEMM v4: 128x128 tile, BK=32, 3-buffer depth-2 counted-vmcnt pipeline ----------
// prologue STAGE(0),STAGE(1); per iter: vmcnt(4) [oldest tile landed, never 0 except last] +
// lgkmcnt(0) + raw s_barrier + sched_barrier(0) -> STAGE(kt+2, free buf) -> 16 MFMA on buf[kt%3].
// Race-free: stage target last read at kt-1; all reads drained (lgkmcnt) before the barrier;
// vmcnt precedes barrier so no wave reads unlanded DMA of another wave.
// LDS rows 64B; content slot c at slot c^(row&3); source col pre-swizzled (rule #21).
// MODE 0: gelu(val+bias[n]) -> bf16 [M][Nout]
// MODE 1: headLN(val+bias[g*768+n]) (+k-norm for g==0) -> bf16 scatter [g][b][h][s][hd]
// MODE 2: val -> fp32 [M][Nout]
// MODE 3: val * sigmoid(extra[m*768+n]+bias[n]) -> fp32 [M][Nout]
template<int MODE>
__global__ __launch_bounds__(256) void gemm_kernel(
    const bf16* __restrict__ A1, int lda1, int K1,
    const bf16* __restrict__ A2, int lda2, int K2, int a2_gstride,
    const bf16* __restrict__ Bw, int ldb, int ngroup,
    const float* __restrict__ bias, const float* __restrict__ extra,
    const float* __restrict__ lng, const float* __restrict__ lnb,
    void* __restrict__ outp, int Nout)
{
  __shared__ bf16 Asm[3][128*32];
  __shared__ bf16 Bsm[3][128*32];
  const int t = threadIdx.x;
  const int w = t>>6, L = t&63;
  const int m0 = blockIdx.x*128, n0 = blockIdx.y*128;
  const int g = blockIdx.z;
  const int wm = w>>1, wn = w&1;
  const int Ktot = K1 + K2;
  const int nk = Ktot >> 5;

  // staging: 2 A + 2 B issues/thread/tile; lane L covers row w*32+i*16+(L>>2), LDS slot L&3.
  // stored content slot = (L&3)^(row&3); row&3 == (L>>2)&3.
  const int srow = L>>2;
  const int scol8 = ((L&3) ^ ((L>>2)&3))*8;   // pre-swizzled source column (elements)

  // frag read offsets (elements), constant across K-loop
  int aoff[4], boff[4];
  #pragma unroll
  for (int f=0;f<4;f++){
    int arow = wm*64 + f*16 + (L&15);
    int brow = wn*64 + f*16 + (L&15);
    aoff[f] = arow*32 + (((L>>4) ^ (arow&3))<<3);
    boff[f] = brow*32 + (((L>>4) ^ (brow&3))<<3);
  }

  const bf16* BrowBase = Bw + (size_t)(g*ngroup + n0)*ldb;

  auto STAGE = [&](int buf, int k0){
    const bf16* Ab; int lda; int acol;
    if (k0 < K1){ Ab = A1; lda = lda1; acol = k0 + scol8; }
    else        { Ab = A2; lda = lda2; acol = (k0-K1) + g*a2_gstride + scol8; }
    #pragma unroll
    for (int i=0;i<2;i++){
      int row = w*32 + i*16 + srow;
      gl_lds(Ab + (size_t)(m0+row)*lda + acol,         &Asm[buf][w*1024 + i*512]);
      gl_lds(BrowBase + (size_t)row*ldb + k0 + scol8,  &Bsm[buf][w*1024 + i*512]);
    }
  };

  f32x4 acc[4][4];
  #pragma unroll
  for (int i=0;i<4;i++)
    #pragma unroll
    for (int j=0;j<4;j++) acc[i][j] = (f32x4){0.f,0.f,0.f,0.f};

  STAGE(0, 0);
  STAGE(1, 32);
  int rd = 0;
  for (int kt=0; kt<nk; ++kt){
    if (kt == nk-1) asm volatile("s_waitcnt vmcnt(0)" ::: "memory");
    else            asm volatile("s_waitcnt vmcnt(4)" ::: "memory");
    asm volatile("s_waitcnt lgkmcnt(0)" ::: "memory");
    __builtin_amdgcn_s_barrier();
    __builtin_amdgcn_sched_barrier(0);
    if (kt+2 < nk){
      int st = rd+2; if (st>=3) st-=3;
      STAGE(st, (kt+2)<<5);
    }
    const bf16* As = Asm[rd];
    const bf16* Bs = Bsm[rd];
    short8 af[4], bfr[4];
    #pragma unroll
    for (int f=0;f<4;f++){
      af[f]  = *(const short8*)&As[aoff[f]];
      bfr[f] = *(const short8*)&Bs[boff[f]];
    }
    #pragma unroll
    for (int i=0;i<4;i++)
      #pragma unroll
      for (int j=0;j<4;j++)
        acc[i][j] = MM(af[i], bfr[j], acc[i][j]);
    rd = (rd==2)?0:rd+1;
  }

  if (MODE==1){
    // fused per-head LN: each wave owns a full 64-wide head per row
    float gco[4], bco[4];
    #pragma unroll
    for (int j=0;j<4;j++){ int cc = j*16 + (L&15); gco[j] = lng[g*64+cc]; bco[j] = lnb[g*64+cc]; }
    #pragma unroll
    for (int i=0;i<4;i++){
      #pragma unroll
      for (int r=0;r<4;r++){
        float v[4];
        #pragma unroll
        for (int j=0;j<4;j++){
          int n = n0 + wn*64 + j*16 + (L&15);
          v[j] = acc[i][j][r] + bias[g*768 + n];
        }
        float s1 = v[0]+v[1]+v[2]+v[3];
        float s2 = v[0]*v[0]+v[1]*v[1]+v[2]*v[2]+v[3]*v[3];
        #pragma unroll
        for (int mk=1; mk<16; mk<<=1){ s1 += __shfl_xor(s1, mk, 64); s2 += __shfl_xor(s2, mk, 64); }
        float mean = s1*(1.f/64.f);
        float var  = s2*(1.f/64.f) - mean*mean;
        float inv  = rsqrtf(var + 1e-5f);
        float y[4];
        #pragma unroll
        for (int j=0;j<4;j++) y[j] = (v[j]-mean)*inv*gco[j] + bco[j];
        if (g==0){
          float n2 = y[0]*y[0]+y[1]*y[1]+y[2]*y[2]+y[3]*y[3];
          #pragma unroll
          for (int mk=1; mk<16; mk<<=1) n2 += __shfl_xor(n2, mk, 64);
          float sc = 1.f/(sqrtf(n2)+1e-6f);
          #pragma unroll
          for (int j=0;j<4;j++) y[j] *= sc;
        }
        int m = m0 + wm*64 + i*16 + (L>>4)*4 + r;
        int b_ = m>>11, s_ = m&2047;
        #pragma unroll
        for (int j=0;j<4;j++){
          int n = n0 + wn*64 + j*16 + (L&15);
          int h_ = n>>6, hd = n&63;
          ((bf16*)outp)[((((size_t)g*B_ + b_)*H_ + h_)*S_ + s_)*HD_ + hd] = __float2bfloat16(y[j]);
        }
      }
    }
  } else {
    #pragma unroll
    for (int i=0;i<4;i++){
      #pragma unroll
      for (int j=0;j<4;j++){
        #pragma unroll
        for (int r=0;r<4;r++){
          int m = m0 + wm*64 + i*16 + (L>>4)*4 + r;
          int n = n0 + wn*64 + j*16 + (L&15);
          float val = acc[i][j][r];
          if (MODE==0){
            if (n < Nout){
              val += bias[n];
              float ge = 0.5f*val*(1.f + erff(val*0.70710678f));
              ((bf16*)outp)[(size_t)m*Nout + n] = __float2bfloat16(ge);
            }
          } else if (MODE==2){
            ((float*)outp)[(size_t)m*Nout + n] = val;
          } else {
            float g2 = extra[(size_t)m*768 + n] + bias[n];
            float gate = 1.f/(1.f + __expf(-g2));
            ((float*)outp)[(size_t)m*Nout + n] = val * gate;
          }
        }
      }
    }
  }
}

// ---------------- chunk prep v2: all-MFMA, packed C^T stores ----------------
__global__ __launch_bounds__(256) void prep_kernel(
    const bf16* __restrict__ kvqb, const float* __restrict__ lr_scale,
    bf16* __restrict__ WKng, bf16* __restrict__ WVTg,
    bf16* __restrict__ AcThi, bf16* __restrict__ AcTlo, bf16* __restrict__ Bcb)
{
  __shared__ __align__(16) char T1[8192]; // Thi -> AcThi
  __shared__ __align__(16) char T2[8192]; // Tlo -> AcTlo
  __shared__ __align__(16) char T3[8192]; // P -> KnT -> WKn
  __shared__ __align__(16) char T4[8192]; // PT -> VT -> WKnT
  __shared__ __align__(16) char T5[8192]; // WVT -> Bc

  const int c = blockIdx.x, bh = blockIdx.y;
  const int h = bh % H_;
  const int t = threadIdx.x, w = t>>6, L = t&63;
  const size_t PS = (size_t)B_*H_*S_*HD_;
  const size_t base_k = (size_t)bh*S_*HD_ + (size_t)c*CH*HD_;
  const float lr = 0.2f/(1.f + __expf(-lr_scale[h]));
  const float beta = 1.f + lr;
  const size_t cb = ((size_t)bh*NCH + c)*4096;
  const bf16* Kg = kvqb + base_k;
  const bf16* Vg = kvqb + PS + base_k;

  const int fr = L&15, fc = (L>>4)*8;
  const int m0 = 16*w + (L>>4)*4;
  const int nb = L&15;   // n = 16*nt + nb

  // ---- phase 0: G = Kn Kn^T; init P=N, PT=N^T, T=I-N (hi/lo)
  {
    short8 aK[2];
    #pragma unroll
    for (int kk=0;kk<2;kk++) aK[kk] = gfrag(Kg, 16*w+fr, kk*32+fc);
    #pragma unroll
    for (int nt=0;nt<4;nt++){
      f32x4 g = (f32x4){0.f,0.f,0.f,0.f};
      #pragma unroll
      for (int kk=0;kk<2;kk++) g = MM(aK[kk], gfrag(Kg, 16*nt+fr, kk*32+fc), g);
      int n = 16*nt + nb;
      float pv[4], ptv[4], tv[4];
      #pragma unroll
      for (int r=0;r<4;r++){
        int m = m0 + r;
        float val = beta*g[r];
        pv[r]  = (n>m)? val : 0.f;
        ptv[r] = (m>n)? val : 0.f;
        tv[r]  = ((n==m)?1.f:0.f) - pv[r];
      }
      stpk(T3, n, m0, pv[0],pv[1],pv[2],pv[3]);
      stpk(T4, n, m0, ptv[0],ptv[1],ptv[2],ptv[3]);
      stpk_hl(T1, T2, n, m0, tv[0],tv[1],tv[2],tv[3]);
    }
  }
  __syncthreads();

  // ---- doubling: s>=1: T += T*N^(2^s); s<=4: square N
  #pragma unroll
  for (int s=0; s<6; ++s){
    const bool do_upd = (s>=1), do_sq = (s<=4);
    f32x4 upd[4], c1[4], c2[4];
    float4 tr[4];
    short8 aPT[2];
    #pragma unroll
    for (int kk=0;kk<2;kk++) aPT[kk] = lfrag(T4, 16*w+fr, kk*32+fc);
    if (do_upd){
      short8 b1[4][2], b2[4][2];
      #pragma unroll
      for (int nt=0;nt<4;nt++){
        #pragma unroll
        for (int kk=0;kk<2;kk++){
          b1[nt][kk] = lfrag(T1, 16*nt+fr, kk*32+fc);
          b2[nt][kk] = lfrag(T2, 16*nt+fr, kk*32+fc);
        }
        upd[nt] = (f32x4){0.f,0.f,0.f,0.f};
      }
      #pragma unroll
      for (int nt=0;nt<4;nt++)
        #pragma unroll
        for (int kk=0;kk<2;kk++){
          upd[nt] = MM(aPT[kk], b1[nt][kk], upd[nt]);
          upd[nt] = MM(aPT[kk], b2[nt][kk], upd[nt]);
        }
      #pragma unroll
      for (int nt=0;nt<4;nt++) tr[nt] = ldpk2(T1, T2, 16*nt+nb, m0);
    }
    if (do_sq){
      short8 aP[2], bPT[4][2], bP[4][2];
      #pragma unroll
      for (int kk=0;kk<2;kk++) aP[kk] = lfrag(T3, 16*w+fr, kk*32+fc);
      #pragma unroll
      for (int nt=0;nt<4;nt++){
        #pragma unroll
        for (int kk=0;kk<2;kk++){
          bPT[nt][kk] = lfrag(T4, 16*nt+fr, kk*32+fc);
          bP[nt][kk]  = lfrag(T3, 16*nt+fr, kk*32+fc);
        }
        c1[nt] = (f32x4){0.f,0.f,0.f,0.f};
        c2[nt] = (f32x4){0.f,0.f,0.f,0.f};
      }
      #pragma unroll
      for (int nt=0;nt<4;nt++)
        #pragma unroll
        for (int kk=0;kk<2;kk++){
          c1[nt] = MM(aP[kk],  bPT[nt][kk], c1[nt]);   // N^2p
          c2[nt] = MM(aPT[kk], bP[nt][kk],  c2[nt]);   // (N^2p)^T
        }
    }
    __syncthreads();
    if (do_upd){
      #pragma unroll
      for (int nt=0;nt<4;nt++){
        int n = 16*nt + nb;
        stpk_hl(T1, T2, n, m0, tr[nt].x+upd[nt][0], tr[nt].y+upd[nt][1],
                               tr[nt].z+upd[nt][2], tr[nt].w+upd[nt][3]);
      }
    }
    if (do_sq){
      #pragma unroll
      for (int nt=0;nt<4;nt++){
        int n = 16*nt + nb;
        stpk(T4, n, m0, c1[nt][0],c1[nt][1],c1[nt][2],c1[nt][3]);  // PT_new
        stpk(T3, n, m0, c2[nt][0],c2[nt][1],c2[nt][2],c2[nt][3]);  // P_new
      }
    }
    __syncthreads();
  }

  // ---- C1: MFMA transposes KnT->T3, VT->T4 (identity B-frags; no LDS reads)
  {
    short8 aKg[2], aVg[2];
    #pragma unroll
    for (int kk=0;kk<2;kk++){
      aKg[kk] = gfrag(Kg, 16*w+fr, kk*32+fc);
      aVg[kk] = gfrag(Vg, 16*w+fr, kk*32+fc);
    }
    #pragma unroll
    for (int nt=0;nt<4;nt++){
      f32x4 ck = (f32x4){0.f,0.f,0.f,0.f};
      f32x4 cv = (f32x4){0.f,0.f,0.f,0.f};
      int row = 16*nt + nb;
      #pragma unroll
      for (int kk=0;kk<2;kk++){
        short8 bi;
        int col0 = kk*32 + fc;
        #pragma unroll
        for (int e=0;e<8;e++) bi[e] = (col0+e == 16*nt+fr) ? (short)0x3F80 : (short)0;
        ck = MM(aKg[kk], bi, ck);
        cv = MM(aVg[kk], bi, cv);
      }
      stpk(T3, row, m0, ck[0],ck[1],ck[2],ck[3]);
      stpk(T4, row, m0, cv[0],cv[1],cv[2],cv[3]);
    }
  }
  __syncthreads();

  // ---- C2: WVT = (T*V)^T -> T5 ; WKnT = (T*Kn)^T -> T4
  {
    short8 a1[2], a2[2];
    #pragma unroll
    for (int kk=0;kk<2;kk++){
      a1[kk] = lfrag(T1, 16*w+fr, kk*32+fc);
      a2[kk] = lfrag(T2, 16*w+fr, kk*32+fc);
    }
    f32x4 cwv[4], cwk[4];
    #pragma unroll
    for (int nt=0;nt<4;nt++){ cwv[nt]=(f32x4){0.f,0.f,0.f,0.f}; cwk[nt]=(f32x4){0.f,0.f,0.f,0.f}; }
    #pragma unroll
    for (int nt=0;nt<4;nt++)
      #pragma unroll
      for (int kk=0;kk<2;kk++){
        short8 bV = lfrag(T4, 16*nt+fr, kk*32+fc);
        cwv[nt] = MM(a1[kk], bV, cwv[nt]);
        cwv[nt] = MM(a2[kk], bV, cwv[nt]);
      }
    #pragma unroll
    for (int nt=0;nt<4;nt++)
      #pragma unroll
      for (int kk=0;kk<2;kk++){
        short8 bK = lfrag(T3, 16*nt+fr, kk*32+fc);
        cwk[nt] = MM(a1[kk], bK, cwk[nt]);
        cwk[nt] = MM(a2[kk], bK, cwk[nt]);
      }
    __syncthreads();
    #pragma unroll
    for (int nt=0;nt<4;nt++){
      int n = 16*nt + nb;
      stpk(T5, n, m0, cwv[nt][0],cwv[nt][1],cwv[nt][2],cwv[nt][3]);
      stpk(T4, n, m0, cwk[nt][0],cwk[nt][1],cwk[nt][2],cwk[nt][3]);
    }
  }
  __syncthreads();

  // ---- C3: Bc -> T5, WKn -> T3, AcT(hi/lo) -> T1/T2 ; bounce WVT(T5) to global
  {
    int row = t>>2, seg = (t&3)*16;
    size_t go = cb + (size_t)row*64 + seg;
    *(short8*)(WVTg+go)   = *(const short8*)(T5 + adr(row,seg));
    *(short8*)(WVTg+go+8) = *(const short8*)(T5 + adr(row,seg+8));

    short8 aK2[2], aWKT[2];
    #pragma unroll
    for (int kk=0;kk<2;kk++){
      aK2[kk]  = lfrag(T3, 16*w+fr, kk*32+fc);
      aWKT[kk] = lfrag(T4, 16*w+fr, kk*32+fc);
    }
    f32x4 cBc[4], cWK[4], cAc[4];
    #pragma unroll
    for (int nt=0;nt<4;nt++){ cBc[nt]=(f32x4){0.f,0.f,0.f,0.f}; cWK[nt]=(f32x4){0.f,0.f,0.f,0.f}; cAc[nt]=(f32x4){0.f,0.f,0.f,0.f}; }
    #pragma unroll
    for (int nt=0;nt<4;nt++)
      #pragma unroll
      for (int kk=0;kk<2;kk++){
        short8 bWVT = lfrag(T5, 16*nt+fr, kk*32+fc);
        cBc[nt] = MM(aK2[kk], bWVT, cBc[nt]);
      }
    #pragma unroll
    for (int nt=0;nt<4;nt++)
      #pragma unroll
      for (int kk=0;kk<2;kk++){
        short8 b1 = lfrag(T1, 16*nt+fr, kk*32+fc);
        short8 b2 = lfrag(T2, 16*nt+fr, kk*32+fc);
        cWK[nt] = MM(aK2[kk], b1, cWK[nt]);
        cWK[nt] = MM(aK2[kk], b2, cWK[nt]);
      }
    #pragma unroll
    for (int nt=0;nt<4;nt++)
      #pragma unroll
      for (int kk=0;kk<2;kk++){
        short8 bK3 = lfrag(T3, 16*nt+fr, kk*32+fc);
        cAc[nt] = MM(aWKT[kk], bK3, cAc[nt]);
      }
    __syncthreads();
    #pragma unroll
    for (int nt=0;nt<4;nt++){
      int n = 16*nt + nb;
      stpk(T5, n, m0, lr*cBc[nt][0], lr*cBc[nt][1], lr*cBc[nt][2], lr*cBc[nt][3]);
      stpk(T3, n, m0, cWK[nt][0],cWK[nt][1],cWK[nt][2],cWK[nt][3]);
      float av[4];
      #pragma unroll
      for (int r=0;r<4;r++) av[r] = ((n==m0+r)?1.f:0.f) - beta*cAc[nt][r];
      stpk_hl(T1, T2, n, m0, av[0],av[1],av[2],av[3]);
    }
  }
  __syncthreads();

  // ---- C4: coalesced bounces to global
  {
    int row = t>>2, seg = (t&3)*16;
    size_t go = cb + (size_t)row*64 + seg;
    *(short8*)(AcThi+go)   = *(const short8*)(T1 + adr(row,seg));
    *(short8*)(AcThi+go+8) = *(const short8*)(T1 + adr(row,seg+8));
    *(short8*)(AcTlo+go)   = *(const short8*)(T2 + adr(row,seg));
    *(short8*)(AcTlo+go+8) = *(const short8*)(T2 + adr(row,seg+8));
    *(short8*)(Bcb+go)     = *(const short8*)(T5 + adr(row,seg));
    *(short8*)(Bcb+go+8)   = *(const short8*)(T5 + adr(row,seg+8));
    *(short8*)(WKng+go)    = *(const short8*)(T3 + adr(row,seg));
    *(short8*)(WKng+go+8)  = *(const short8*)(T3 + adr(row,seg+8));
  }
}

// ---------------- sequential chunk recurrence: M <- M*Ac + Bc (48 blocks) ----------------
__global__ __launch_bounds__(256) void seq_kernel(
    const bf16* __restrict__ AcThi, const bf16* __restrict__ AcTlo,
    const bf16* __restrict__ Bcb,
    bf16* __restrict__ Mpref, bf16* __restrict__ Mplo, float* __restrict__ Mout)
{
  __shared__ __align__(16) char sM[4][2][2048];
  const int bh = blockIdx.x;
  const int t = threadIdx.x, w = t>>6, L = t&63;
  char* mhi = sM[w][0]; char* mlo = sM[w][1];
  const size_t cbase = (size_t)bh*NCH*4096;

  { float4 z = {0.f,0.f,0.f,0.f};
    #pragma unroll
    for (int i=0;i<2;i++){ ((float4*)mhi)[L + 64*i] = z; ((float4*)mlo)[L + 64*i] = z; } }
  { short8 z = {0,0,0,0,0,0,0,0};
    #pragma unroll
    for (int i=0;i<2;i++){
      ((short8*)(Mpref + cbase))[t + 256*i] = z;
      ((short8*)(Mplo  + cbase))[t + 256*i] = z;
    } }

  short8 Xbh[4][2], Xbl[4][2]; float Xbc[4][4];
  short8 Ybh[4][2], Ybl[4][2]; float Ybc[4][4];

  auto loadf = [&](short8 (&fbh)[4][2], short8 (&fbl)[4][2], float (&fbc)[4][4], int c){
    size_t cb = cbase + (size_t)c*4096;
    #pragma unroll
    for (int nt=0;nt<4;nt++){
      #pragma unroll
      for (int kk=0;kk<2;kk++){
        size_t o = cb + (size_t)(16*nt + (L&15))*64 + kk*32 + (L>>4)*8;
        fbh[nt][kk] = *(const short8*)(AcThi + o);
        fbl[nt][kk] = *(const short8*)(AcTlo + o);
      }
      #pragma unroll
      for (int r=0;r<4;r++)
        fbc[nt][r] = us2f(*(const unsigned short*)(Bcb + cb + (size_t)(16*w + (L>>4)*4 + r)*64 + nt*16 + (L&15)));
    }
  };
  auto compute = [&](short8 (&fbh)[4][2], short8 (&fbl)[4][2], float (&fbc)[4][4], int c){
    short8 ah[2], al[2];
    #pragma unroll
    for (int kk=0;kk<2;kk++){
      ah[kk] = lfrag(mhi, L&15, kk*32 + (L>>4)*8);
      al[kk] = lfrag(mlo, L&15, kk*32 + (L>>4)*8);
    }
    #pragma unroll
    for (int nt=0;nt<4;nt++){
      f32x4 acc = { fbc[nt][0], fbc[nt][1], fbc[nt][2], fbc[nt][3] };
      acc = MM(ah[0], fbh[nt][0], acc);
      acc = MM(ah[1], fbh[nt][1], acc);
      acc = MM(ah[0], fbl[nt][0], acc);
      acc = MM(ah[1], fbl[nt][1], acc);
      acc = MM(al[0], fbh[nt][0], acc);
      acc = MM(al[1], fbh[nt][1], acc);
      #pragma unroll
      for (int r=0;r<4;r++){
        float f = acc[r];
        bf16 hi = __float2bfloat16(f);
        float lo = f - bf2f(hi);
        int lrow = (L>>4)*4 + r, col = nt*16 + (L&15);
        int off = ((lrow*128 + col*2) ^ ((lrow&7)<<4));
        *(bf16*)(mhi + off) = hi;
        *(bf16*)(mlo + off) = __float2bfloat16(lo);
        if (c < NCH-1){
          size_t go = cbase + (size_t)(c+1)*4096 + (size_t)(16*w + lrow)*64 + col;
          Mpref[go] = hi;
          Mplo[go]  = __float2bfloat16(lo);
        } else {
          Mout[((size_t)bh*64 + 16*w + lrow)*64 + col] = f;
        }
      }
    }
  };

  loadf(Xbh,Xbl,Xbc,0);
  for (int c=0;c<NCH;c+=2){
    loadf(Ybh,Ybl,Ybc,c+1);
    compute(Xbh,Xbl,Xbc,c);
    if (c+2 < NCH) loadf(Xbh,Xbl,Xbc,c+2);
    compute(Ybh,Ybl,Ybc,c+1);
  }
}

// ---------------- parallel output phase ----------------
// out = Q M0^T + Atil * U,  U = lr*WV - beta*(WKn M0^T);  Atil computed in-kernel
// M0 consumed in hi+lo bf16 (fp32-grade) for accuracy.
__global__ __launch_bounds__(256) void outphase_kernel(
    const bf16* __restrict__ kvqb, const bf16* __restrict__ Mpref, const bf16* __restrict__ Mplo,
    const bf16* __restrict__ WKng, const bf16* __restrict__ WVTb,
    const float* __restrict__ lr_scale, bf16* __restrict__ attn)
{
  __shared__ __align__(16) char sUT[8192];
  __shared__ __align__(16) char sAT[8192];
  const int c = blockIdx.x, bh = blockIdx.y;
  const int b = bh / H_, h = bh % H_;
  const int t = threadIdx.x, w = t>>6, L = t&63;
  const size_t PS = (size_t)B_*H_*S_*HD_;
  const size_t cb = ((size_t)bh*NCH + c)*4096;
  const size_t base_k = (size_t)bh*S_*HD_ + (size_t)c*CH*HD_;
  const bf16* Kg = kvqb + base_k;
  const bf16* Qg = kvqb + 2*PS + base_k;
  const float lr = 0.2f/(1.f + __expf(-lr_scale[h]));
  const float beta = 1.f + lr;
  const int fr = L&15, fc = (L>>4)*8;
  const int m0 = 16*w + (L>>4)*4;
  const int nb = L&15;

  // Atil tile: Z[t][i] = (i<t)? (Q Kn^T)[t][i] : 0   via TILE(Kn,Q) + packed C^T store
  {
    short8 aKn[2];
    #pragma unroll
    for (int kk=0;kk<2;kk++) aKn[kk] = gfrag(Kg, 16*w+fr, kk*32+fc);
    #pragma unroll
    for (int nt=0;nt<4;nt++){
      f32x4 cat = (f32x4){0.f,0.f,0.f,0.f};
      #pragma unroll
      for (int kk=0;kk<2;kk++) cat = MM(aKn[kk], gfrag(Qg, 16*nt+fr, kk*32+fc), cat);
      int n = 16*nt + nb;
      float v[4];
      #pragma unroll
      for (int r=0;r<4;r++) v[r] = (m0+r < n)? cat[r] : 0.f;
      stpk(sAT, n, m0, v[0],v[1],v[2],v[3]);
    }
  }

  short8 mbh[4][2], mbl[4][2], qa[2], wa[2];
  #pragma unroll
  for (int kk=0;kk<2;kk++){
    qa[kk] = gfrag(Qg, 16*w+fr, kk*32+fc);
    wa[kk] = *(const short8*)(WKng + cb + (size_t)(16*w + fr)*64 + kk*32 + fc);
  }
  #pragma unroll
  for (int nt=0;nt<4;nt++)
    #pragma unroll
    for (int kk=0;kk<2;kk++){
      size_t o = cb + (size_t)(16*nt + fr)*64 + kk*32 + fc;
      mbh[nt][kk] = *(const short8*)(Mpref + o);
      mbl[nt][kk] = *(const short8*)(Mplo  + o);
    }
  f32x4 aout[4], ap[4];
  #pragma unroll
  for (int nt=0;nt<4;nt++){ aout[nt]=(f32x4){0.f,0.f,0.f,0.f}; ap[nt]=(f32x4){0.f,0.f,0.f,0.f}; }
  #pragma unroll
  for (int nt=0;nt<4;nt++)
    #pragma unroll
    for (int kk=0;kk<2;kk++){
      aout[nt] = MM(qa[kk], mbh[nt][kk], aout[nt]);
      aout[nt] = MM(qa[kk], mbl[nt][kk], aout[nt]);
      ap[nt]   = MM(wa[kk], mbh[nt][kk], ap[nt]);
      ap[nt]   = MM(wa[kk], mbl[nt][kk], ap[nt]);
    }
  #pragma unroll
  for (int nt=0;nt<4;nt++){
    s16x4 wv4 = *(const s16x4*)(WVTb + cb + (size_t)(nt*16 + (L&15))*64 + 16*w + (L>>4)*4);
    short us[4];
    #pragma unroll
    for (int r=0;r<4;r++){
      float wv = us2f((unsigned short)wv4[r]);
      us[r] = f2s(lr*wv - beta*ap[nt][r]);
    }
    int d = nt*16 + (L&15);
    int i0 = 16*w + (L>>4)*4;
    s16x4 pk = { us[0], us[1], us[2], us[3] };
    *(s16x4*)(sUT + adr(d, i0)) = pk;
  }
  __syncthreads();
  short8 ta[2], ub[4][2];
  #pragma unroll
  for (int kk=0;kk<2;kk++)
    ta[kk] = lfrag(sAT, 16*w+fr, kk*32+fc);
  #pragma unroll
  for (int nt=0;nt<4;nt++)
    #pragma unroll
    for (int kk=0;kk<2;kk++)
      ub[nt][kk] = lfrag(sUT, 16*nt + fr, kk*32 + fc);
  #pragma unroll
  for (int nt=0;nt<4;nt++)
    #pragma unroll
    for (int kk=0;kk<2;kk++)
      aout[nt] = MM(ta[kk], ub[nt][kk], aout[nt]);
  #pragma unroll
  for (int nt=0;nt<4;nt++)
    #pragma unroll
    for (int r=0;r<4;r++)
      attn[((size_t)b*S_ + (size_t)c*CH + 16*w + (L>>4)*4 + r)*P_ + h*HD_ + nt*16 + (L&15)]
        = __float2bfloat16(aout[nt][r]);
}

extern "C" void kernel_launch(void* const* d_in, const int* in_sizes, int n_in,
                              void* d_out, int out_size, void* d_ws, size_t ws_size,
                              hipStream_t stream)
{
  const float* x     = (const float*)d_in[0];
  const float* ln_g  = (const float*)d_in[1];
  const float* ln_b  = (const float*)d_in[2];
  const float* Wk    = (const float*)d_in[3];
  const float* Wv    = (const float*)d_in[4];
  const float* Wq    = (const float*)d_in[5];
  const float* km_w1 = (const float*)d_in[6];  const float* km_b1 = (const float*)d_in[7];
  const float* km_w2 = (const float*)d_in[8];  const float* km_b2 = (const float*)d_in[9];
  const float* vm_w1 = (const float*)d_in[10]; const float* vm_b1 = (const float*)d_in[11];
  const float* vm_w2 = (const float*)d_in[12]; const float* vm_b2 = (const float*)d_in[13];
  const float* qm_w1 = (const float*)d_in[14]; const float* qm_b1 = (const float*)d_in[15];
  const float* qm_w2 = (const float*)d_in[16]; const float* qm_b2 = (const float*)d_in[17];
  const float* lnk_g = (const float*)d_in[18]; const float* lnk_b = (const float*)d_in[19];
  const float* lnv_g = (const float*)d_in[20]; const float* lnv_b = (const float*)d_in[21];
  const float* lnq_g = (const float*)d_in[22]; const float* lnq_b = (const float*)d_in[23];
  const float* Wo    = (const float*)d_in[24];
  const float* lr_sc = (const float*)d_in[25];
  const float* Wg    = (const float*)d_in[26];
  const float* bg    = (const float*)d_in[27];

  const size_t CHB = (size_t)BH*NCH*4096;

  char* ws = (char*)d_ws;
  size_t o = 0;
  bf16* xnb   = (bf16*)(ws + o); o += (size_t)M_*D_*2;
  bf16* xb    = (bf16*)(ws + o); o += (size_t)M_*D_*2;
  bf16* Hb    = (bf16*)(ws + o); o += (size_t)M_*576*2;
  bf16* kvqb  = (bf16*)(ws + o); o += (size_t)3*M_*P_*2;
  bf16* attn  = (bf16*)(ws + o); o += (size_t)M_*P_*2;
  size_t o_p = o;
  bf16* AcThi = (bf16*)(ws + o); o += CHB*2;
  bf16* AcTlo = (bf16*)(ws + o); o += CHB*2;
  bf16* Bcb   = (bf16*)(ws + o); o += CHB*2;
  bf16* WVTb  = (bf16*)(ws + o); o += CHB*2;
  bf16* WKng  = (bf16*)(ws + o); o += CHB*2;
  bf16* Mpref = (bf16*)(ws + o); o += CHB*2;
  bf16* Mplo  = (bf16*)(ws + o); o += CHB*2;
  bf16* Whb   = (bf16*)(ws + o); o += (size_t)640*768*2;
  bf16* Wkvqb = (bf16*)(ws + o); o += (size_t)2304*960*2;
  bf16* Wob   = (bf16*)(ws + o); o += (size_t)768*768*2;
  bf16* Wgb   = (bf16*)(ws + o); o += (size_t)768*768*2;
  float* biasb= (float*)(ws + o); o += 3264*4;
  // G2 overlays AcThi+AcTlo (dead after seq; outphase doesn't touch them)
  float* G2   = (float*)(ws + o_p);

  float* outF = (float*)d_out;
  float* Mout = outF + (size_t)M_*D_;

  pack_all_kernel<<<15181, 256, 0, stream>>>(
      km_w1, vm_w1, qm_w1, Wk, Wv, Wq, km_w2, vm_w2, qm_w2, Wo, Wg,
      km_b1, vm_b1, qm_b1, km_b2, vm_b2, qm_b2,
      lnk_g, lnv_g, lnq_g, lnk_b, lnv_b, lnq_b,
      Whb, Wkvqb, Wob, Wgb, biasb);

  ln_in_kernel<<<M_, 256, 0, stream>>>(x, ln_g, ln_b, xnb, xb);

  gemm_kernel<0><<<dim3(64,5,1), 256, 0, stream>>>(xnb, 768, 768, nullptr, 0, 0, 0,
                                                   Whb, 768, 640, biasb, nullptr, nullptr, nullptr, Hb, 576);
  gemm_kernel<1><<<dim3(64,6,3), 256, 0, stream>>>(xnb, 768, 768, Hb, 576, 192, 192,
                                                   Wkvqb, 960, 768, biasb + 576, nullptr,
                                                   biasb + 2880, biasb + 3072, kvqb, 768);

  prep_kernel<<<dim3(NCH, BH), 256, 0, stream>>>(kvqb, lr_sc, WKng, WVTb, AcThi, AcTlo, Bcb);
  seq_kernel<<<BH, 256, 0, stream>>>(AcThi, AcTlo, Bcb, Mpref, Mplo, Mout);
  outphase_kernel<<<dim3(NCH, BH), 256, 0, stream>>>(kvqb, Mpref, Mplo, WKng, WVTb, lr_sc, attn);

  // G2 = x @ Wg^T (fp32), then fused out = (attn @ Wo^T) * sigmoid(G2 + bg)
  gemm_kernel<2><<<dim3(64,6,1), 256, 0, stream>>>(xb, 768, 768, nullptr, 0, 0, 0,
                                                   Wgb, 768, 768, nullptr, nullptr, nullptr, nullptr, G2, 768);
  gemm_kernel<3><<<dim3(64,6,1), 256, 0, stream>>>(attn, 768, 768, nullptr, 0, 0, 0,
                                                   Wob, 768, 768, bg, G2, nullptr, nullptr, outF, 768);
}

// Round 8
// 245.389 us; speedup vs baseline: 1.2505x; 1.2505x over previous
//
#include <hip/hip_runtime.h>
#include <hip/hip_bf16.h>
#include <math.h>

#define B_ 4
#define S_ 2048
#define D_ 768
#define H_ 12
#define HD_ 64
#define P_ 768
#define M_ (B_*S_)   // 8192
#define NCH 32       // chunks per sequence
#define CH 64        // chunk length
#define BH (B_*H_)   // 48

typedef __hip_bfloat16 bf16;
typedef __attribute__((ext_vector_type(8))) short short8;
typedef __attribute__((ext_vector_type(4))) short s16x4;
typedef __attribute__((ext_vector_type(4))) float f32x4;

__device__ __forceinline__ float wave_reduce_sum(float v){
  #pragma unroll
  for (int off=32; off>0; off>>=1) v += __shfl_xor(v, off, 64);
  return v;
}
__device__ __forceinline__ float bf2f(bf16 h){ return __bfloat162float(h); }
__device__ __forceinline__ float us2f(unsigned short u){
  union{unsigned int i; float f;} z; z.i = ((unsigned int)u)<<16; return z.f;
}
// swizzled LDS [64][64] bf16 tiles (128B rows): byte ^= (row&7)<<4
__device__ __forceinline__ int adr(int row, int col){ return (row*128 + col*2) ^ ((row&7)<<4); }
__device__ __forceinline__ short8 lfrag(const char* base, int row, int col){
  return *(const short8*)(base + adr(row,col));
}
__device__ __forceinline__ short8 gfrag(const bf16* g, int row, int col){
  return *(const short8*)(g + row*64 + col);
}
__device__ __forceinline__ f32x4 MM(short8 a, short8 b, f32x4 c){
  return __builtin_amdgcn_mfma_f32_16x16x32_bf16(a, b, c, 0,0,0);
}
__device__ __forceinline__ short f2s(float v){ bf16 h = __float2bfloat16(v); return *(short*)&h; }
// packed C^T store: lane's 4 values C[m0..m0+3][n] -> tile[n][m0..m0+3]
__device__ __forceinline__ void stpk(char* b, int n, int m0, float v0,float v1,float v2,float v3){
  s16x4 p = { f2s(v0), f2s(v1), f2s(v2), f2s(v3) };
  *(s16x4*)(b + adr(n, m0)) = p;
}
__device__ __forceinline__ void stpk_hl(char* bh, char* bl, int n, int m0,
                                        float v0,float v1,float v2,float v3){
  float h0=bf2f(__float2bfloat16(v0)), h1=bf2f(__float2bfloat16(v1));
  float h2=bf2f(__float2bfloat16(v2)), h3=bf2f(__float2bfloat16(v3));
  stpk(bh, n, m0, h0,h1,h2,h3);
  stpk(bl, n, m0, v0-h0, v1-h1, v2-h2, v3-h3);
}
__device__ __forceinline__ float4 ldpk2(const char* bh, const char* bl, int n, int m0){
  s16x4 a = *(const s16x4*)(bh + adr(n,m0));
  s16x4 b = *(const s16x4*)(bl + adr(n,m0));
  return make_float4(us2f((unsigned short)a[0])+us2f((unsigned short)b[0]),
                     us2f((unsigned short)a[1])+us2f((unsigned short)b[1]),
                     us2f((unsigned short)a[2])+us2f((unsigned short)b[2]),
                     us2f((unsigned short)a[3])+us2f((unsigned short)b[3]));
}
// async global->LDS, 16B per lane, LDS dest = wave-uniform base + lane*16
__device__ __forceinline__ void gl_lds(const bf16* g, const bf16* l){
  __builtin_amdgcn_global_load_lds(
      (const __attribute__((address_space(1))) void*)g,
      (__attribute__((address_space(3))) void*)l, 16, 0, 0);
}

// ---------------- merged weight/bias packing + input layernorm ----------------
__global__ __launch_bounds__(256) void pack_ln_kernel(
    const float* __restrict__ km1,const float* __restrict__ vm1,const float* __restrict__ qm1,
    const float* __restrict__ Wk,const float* __restrict__ Wv,const float* __restrict__ Wq,
    const float* __restrict__ k2,const float* __restrict__ v2,const float* __restrict__ q2,
    const float* __restrict__ Wo,const float* __restrict__ Wg,
    const float* __restrict__ kb1,const float* __restrict__ vb1,const float* __restrict__ qb1,
    const float* __restrict__ kb2,const float* __restrict__ vb2,const float* __restrict__ qb2,
    const float* __restrict__ lnkg,const float* __restrict__ lnvg,const float* __restrict__ lnqg,
    const float* __restrict__ lnkb,const float* __restrict__ lnvb,const float* __restrict__ lnqb,
    bf16* __restrict__ Whb, bf16* __restrict__ Wkvqb, bf16* __restrict__ Wob,
    bf16* __restrict__ Wgb, float* __restrict__ biasb,
    const float* __restrict__ x, const float* __restrict__ lng_in, const float* __restrict__ lnb_in,
    bf16* __restrict__ xn, bf16* __restrict__ xb)
{
  if (blockIdx.x >= 15181){
    // ---- input layernorm path ----
    int row = blockIdx.x - 15181;
    const float* xr = x + (size_t)row*D_;
    int t = threadIdx.x;
    float v0 = xr[t], v1 = xr[t+256], v2 = xr[t+512];
    float s  = v0+v1+v2;
    float sq = v0*v0+v1*v1+v2*v2;
    s = wave_reduce_sum(s); sq = wave_reduce_sum(sq);
    __shared__ float red[8];
    int w = t>>6;
    if ((t&63)==0){ red[w]=s; red[4+w]=sq; }
    __syncthreads();
    s  = red[0]+red[1]+red[2]+red[3];
    sq = red[4]+red[5]+red[6]+red[7];
    float mean = s*(1.f/D_);
    float var  = sq*(1.f/D_) - mean*mean;
    float inv  = rsqrtf(var + 1e-5f);
    bf16* xnr = xn + (size_t)row*D_;
    bf16* xbr = xb + (size_t)row*D_;
    xnr[t]     = __float2bfloat16((v0-mean)*inv*lng_in[t]     + lnb_in[t]);
    xnr[t+256] = __float2bfloat16((v1-mean)*inv*lng_in[t+256] + lnb_in[t+256]);
    xnr[t+512] = __float2bfloat16((v2-mean)*inv*lng_in[t+512] + lnb_in[t+512]);
    xbr[t] = __float2bfloat16(v0); xbr[t+256] = __float2bfloat16(v1); xbr[t+512] = __float2bfloat16(v2);
    return;
  }
  int i = blockIdx.x*256 + threadIdx.x;
  if (i < 491520){                       // Wh pad 640x768
    int r = i/768, c = i%768;
    float v = 0.f;
    if (r < 192) v = km1[r*768+c];
    else if (r < 384) v = vm1[(r-192)*768+c];
    else if (r < 576) v = qm1[(r-384)*768+c];
    Whb[i] = __float2bfloat16(v);
  } else if (i < 2703360){               // Wkvq 2304x960
    int i2 = i - 491520;
    int r = i2/960, c = i2%960;
    int p = r/768, rr = r%768;
    const float* W  = (p==0)?Wk:(p==1)?Wv:Wq;
    const float* w2 = (p==0)?k2:(p==1)?v2:q2;
    float v = (c < 768) ? W[(size_t)rr*768+c] : 0.1f*w2[(size_t)rr*192 + (c-768)];
    Wkvqb[i2] = __float2bfloat16(v);
  } else if (i < 3293184){
    int i2 = i - 2703360;
    Wob[i2] = __float2bfloat16(Wo[i2]);
  } else if (i < 3883008){
    int i2 = i - 3293184;
    Wgb[i2] = __float2bfloat16(Wg[i2]);
  } else if (i < 3886272){
    int i2 = i - 3883008;                // 3264 floats
    if (i2 < 576){
      biasb[i2] = (i2<192)? kb1[i2] : (i2<384)? vb1[i2-192] : qb1[i2-384];
    } else if (i2 < 2880){
      int r = i2-576; int p = r/768, rr = r%768;
      const float* b2 = (p==0)?kb2:(p==1)?vb2:qb2;
      biasb[i2] = 0.1f*b2[rr];
    } else if (i2 < 3072){
      int k3 = i2-2880; int gg=k3/64, cc=k3%64;
      biasb[i2] = (gg==0?lnkg:gg==1?lnvg:lnqg)[cc];
    } else {
      int k3 = i2-3072; int gg=k3/64, cc=k3%64;
      biasb[i2] = (gg==0?lnkb:gg==1?lnvb:lnqb)[cc];
    }
  }
}

// ---------------- GEMM core: 128x128 tile, BK=32, 3-buffer depth-2 counted-vmcnt pipeline ------
// MODE 0: gelu(val+bias[n]) -> bf16 [M][Nout]
// MODE 1: headLN(val+bias[g*768+n]) (+k-norm for g==0) -> bf16 scatter [g][b][h][s][hd]
// MODE 3: val * sigmoid(bf16_extra[m*768+n]+bias[n]) -> fp32 [M][Nout]
// MODE 4: val -> bf16 [M][Nout]
template<int MODE>
__device__ __forceinline__ void gemm_core(
    const bf16* __restrict__ A1, int lda1, int K1,
    const bf16* __restrict__ A2, int lda2, int K2, int a2_gstride,
    const bf16* __restrict__ Bw, int ldb, int ngroup,
    const float* __restrict__ bias, const void* __restrict__ extra,
    const float* __restrict__ lng, const float* __restrict__ lnb,
    void* __restrict__ outp, int Nout,
    int bx, int by, int g, char* smemraw)
{
  bf16 (*Asm)[128*32] = (bf16 (*)[128*32])smemraw;
  bf16 (*Bsm)[128*32] = (bf16 (*)[128*32])(smemraw + 3*128*32*2);
  const int t = threadIdx.x;
  const int w = t>>6, L = t&63;
  const int m0 = bx*128, n0 = by*128;
  const int wm = w>>1, wn = w&1;
  const int Ktot = K1 + K2;
  const int nk = Ktot >> 5;

  const int srow = L>>2;
  const int scol8 = ((L&3) ^ ((L>>2)&3))*8;   // pre-swizzled source column (elements)

  int aoff[4], boff[4];
  #pragma unroll
  for (int f=0;f<4;f++){
    int arow = wm*64 + f*16 + (L&15);
    int brow = wn*64 + f*16 + (L&15);
    aoff[f] = arow*32 + (((L>>4) ^ (arow&3))<<3);
    boff[f] = brow*32 + (((L>>4) ^ (brow&3))<<3);
  }

  const bf16* BrowBase = Bw + (size_t)(g*ngroup + n0)*ldb;

  auto STAGE = [&](int buf, int k0){
    const bf16* Ab; int lda; int acol;
    if (k0 < K1){ Ab = A1; lda = lda1; acol = k0 + scol8; }
    else        { Ab = A2; lda = lda2; acol = (k0-K1) + g*a2_gstride + scol8; }
    #pragma unroll
    for (int i=0;i<2;i++){
      int row = w*32 + i*16 + srow;
      gl_lds(Ab + (size_t)(m0+row)*lda + acol,         &Asm[buf][w*1024 + i*512]);
      gl_lds(BrowBase + (size_t)row*ldb + k0 + scol8,  &Bsm[buf][w*1024 + i*512]);
    }
  };

  f32x4 acc[4][4];
  #pragma unroll
  for (int i=0;i<4;i++)
    #pragma unroll
    for (int j=0;j<4;j++) acc[i][j] = (f32x4){0.f,0.f,0.f,0.f};

  STAGE(0, 0);
  STAGE(1, 32);
  int rd = 0;
  for (int kt=0; kt<nk; ++kt){
    if (kt == nk-1) asm volatile("s_waitcnt vmcnt(0)" ::: "memory");
    else            asm volatile("s_waitcnt vmcnt(4)" ::: "memory");
    asm volatile("s_waitcnt lgkmcnt(0)" ::: "memory");
    __builtin_amdgcn_s_barrier();
    __builtin_amdgcn_sched_barrier(0);
    if (kt+2 < nk){
      int st = rd+2; if (st>=3) st-=3;
      STAGE(st, (kt+2)<<5);
    }
    const bf16* As = Asm[rd];
    const bf16* Bs = Bsm[rd];
    short8 af[4], bfr[4];
    #pragma unroll
    for (int f=0;f<4;f++){
      af[f]  = *(const short8*)&As[aoff[f]];
      bfr[f] = *(const short8*)&Bs[boff[f]];
    }
    #pragma unroll
    for (int i=0;i<4;i++)
      #pragma unroll
      for (int j=0;j<4;j++)
        acc[i][j] = MM(af[i], bfr[j], acc[i][j]);
    rd = (rd==2)?0:rd+1;
  }

  if (MODE==1){
    float gco[4], bco[4];
    #pragma unroll
    for (int j=0;j<4;j++){ int cc = j*16 + (L&15); gco[j] = lng[g*64+cc]; bco[j] = lnb[g*64+cc]; }
    #pragma unroll
    for (int i=0;i<4;i++){
      #pragma unroll
      for (int r=0;r<4;r++){
        float v[4];
        #pragma unroll
        for (int j=0;j<4;j++){
          int n = n0 + wn*64 + j*16 + (L&15);
          v[j] = acc[i][j][r] + bias[g*768 + n];
        }
        float s1 = v[0]+v[1]+v[2]+v[3];
        float s2 = v[0]*v[0]+v[1]*v[1]+v[2]*v[2]+v[3]*v[3];
        #pragma unroll
        for (int mk=1; mk<16; mk<<=1){ s1 += __shfl_xor(s1, mk, 64); s2 += __shfl_xor(s2, mk, 64); }
        float mean = s1*(1.f/64.f);
        float var  = s2*(1.f/64.f) - mean*mean;
        float inv  = rsqrtf(var + 1e-5f);
        float y[4];
        #pragma unroll
        for (int j=0;j<4;j++) y[j] = (v[j]-mean)*inv*gco[j] + bco[j];
        if (g==0){
          float n2 = y[0]*y[0]+y[1]*y[1]+y[2]*y[2]+y[3]*y[3];
          #pragma unroll
          for (int mk=1; mk<16; mk<<=1) n2 += __shfl_xor(n2, mk, 64);
          float sc = 1.f/(sqrtf(n2)+1e-6f);
          #pragma unroll
          for (int j=0;j<4;j++) y[j] *= sc;
        }
        int m = m0 + wm*64 + i*16 + (L>>4)*4 + r;
        int b_ = m>>11, s_ = m&2047;
        #pragma unroll
        for (int j=0;j<4;j++){
          int n = n0 + wn*64 + j*16 + (L&15);
          int h_ = n>>6, hd = n&63;
          ((bf16*)outp)[((((size_t)g*B_ + b_)*H_ + h_)*S_ + s_)*HD_ + hd] = __float2bfloat16(y[j]);
        }
      }
    }
  } else {
    #pragma unroll
    for (int i=0;i<4;i++){
      #pragma unroll
      for (int j=0;j<4;j++){
        #pragma unroll
        for (int r=0;r<4;r++){
          int m = m0 + wm*64 + i*16 + (L>>4)*4 + r;
          int n = n0 + wn*64 + j*16 + (L&15);
          float val = acc[i][j][r];
          if (MODE==0){
            if (n < Nout){
              val += bias[n];
              float ge = 0.5f*val*(1.f + erff(val*0.70710678f));
              ((bf16*)outp)[(size_t)m*Nout + n] = __float2bfloat16(ge);
            }
          } else if (MODE==4){
            ((bf16*)outp)[(size_t)m*Nout + n] = __float2bfloat16(val);
          } else {
            float g2 = bf2f(((const bf16*)extra)[(size_t)m*768 + n]) + bias[n];
            float gate = 1.f/(1.f + __expf(-g2));
            ((float*)outp)[(size_t)m*Nout + n] = val * gate;
          }
        }
      }
    }
  }
}

template<int MODE>
__global__ __launch_bounds__(256) void gemm_kernel(
    const bf16* __restrict__ A1, int lda1, int K1,
    const bf16* __restrict__ A2, int lda2, int K2, int a2_gstride,
    const bf16* __restrict__ Bw, int ldb, int ngroup,
    const float* __restrict__ bias, const void* __restrict__ extra,
    const float* __restrict__ lng, const float* __restrict__ lnb,
    void* __restrict__ outp, int Nout)
{
  __shared__ __align__(16) char smem[49152];
  gemm_core<MODE>(A1, lda1, K1, A2, lda2, K2, a2_gstride, Bw, ldb, ngroup,
                  bias, extra, lng, lnb, outp, Nout,
                  blockIdx.x, blockIdx.y, blockIdx.z, smem);
}

// ---------------- chunk prep: all-MFMA, packed C^T stores (unchanged from R7) ----------------
__global__ __launch_bounds__(256) void prep_kernel(
    const bf16* __restrict__ kvqb, const float* __restrict__ lr_scale,
    bf16* __restrict__ WKng, bf16* __restrict__ WVTg,
    bf16* __restrict__ AcThi, bf16* __restrict__ AcTlo, bf16* __restrict__ Bcb)
{
  __shared__ __align__(16) char T1[8192]; // Thi -> AcThi
  __shared__ __align__(16) char T2[8192]; // Tlo -> AcTlo
  __shared__ __align__(16) char T3[8192]; // P -> KnT -> WKn
  __shared__ __align__(16) char T4[8192]; // PT -> VT -> WKnT
  __shared__ __align__(16) char T5[8192]; // WVT -> Bc

  const int c = blockIdx.x, bh = blockIdx.y;
  const int h = bh % H_;
  const int t = threadIdx.x, w = t>>6, L = t&63;
  const size_t PS = (size_t)B_*H_*S_*HD_;
  const size_t base_k = (size_t)bh*S_*HD_ + (size_t)c*CH*HD_;
  const float lr = 0.2f/(1.f + __expf(-lr_scale[h]));
  const float beta = 1.f + lr;
  const size_t cb = ((size_t)bh*NCH + c)*4096;
  const bf16* Kg = kvqb + base_k;
  const bf16* Vg = kvqb + PS + base_k;

  const int fr = L&15, fc = (L>>4)*8;
  const int m0 = 16*w + (L>>4)*4;
  const int nb = L&15;   // n = 16*nt + nb

  // ---- phase 0: G = Kn Kn^T; init P=N, PT=N^T, T=I-N (hi/lo)
  {
    short8 aK[2];
    #pragma unroll
    for (int kk=0;kk<2;kk++) aK[kk] = gfrag(Kg, 16*w+fr, kk*32+fc);
    #pragma unroll
    for (int nt=0;nt<4;nt++){
      f32x4 g = (f32x4){0.f,0.f,0.f,0.f};
      #pragma unroll
      for (int kk=0;kk<2;kk++) g = MM(aK[kk], gfrag(Kg, 16*nt+fr, kk*32+fc), g);
      int n = 16*nt + nb;
      float pv[4], ptv[4], tv[4];
      #pragma unroll
      for (int r=0;r<4;r++){
        int m = m0 + r;
        float val = beta*g[r];
        pv[r]  = (n>m)? val : 0.f;
        ptv[r] = (m>n)? val : 0.f;
        tv[r]  = ((n==m)?1.f:0.f) - pv[r];
      }
      stpk(T3, n, m0, pv[0],pv[1],pv[2],pv[3]);
      stpk(T4, n, m0, ptv[0],ptv[1],ptv[2],ptv[3]);
      stpk_hl(T1, T2, n, m0, tv[0],tv[1],tv[2],tv[3]);
    }
  }
  __syncthreads();

  // ---- doubling: s>=1: T += T*N^(2^s); s<=4: square N
  #pragma unroll
  for (int s=0; s<6; ++s){
    const bool do_upd = (s>=1), do_sq = (s<=4);
    f32x4 upd[4], c1[4], c2[4];
    float4 tr[4];
    short8 aPT[2];
    #pragma unroll
    for (int kk=0;kk<2;kk++) aPT[kk] = lfrag(T4, 16*w+fr, kk*32+fc);
    if (do_upd){
      short8 b1[4][2], b2[4][2];
      #pragma unroll
      for (int nt=0;nt<4;nt++){
        #pragma unroll
        for (int kk=0;kk<2;kk++){
          b1[nt][kk] = lfrag(T1, 16*nt+fr, kk*32+fc);
          b2[nt][kk] = lfrag(T2, 16*nt+fr, kk*32+fc);
        }
        upd[nt] = (f32x4){0.f,0.f,0.f,0.f};
      }
      #pragma unroll
      for (int nt=0;nt<4;nt++)
        #pragma unroll
        for (int kk=0;kk<2;kk++){
          upd[nt] = MM(aPT[kk], b1[nt][kk], upd[nt]);
          upd[nt] = MM(aPT[kk], b2[nt][kk], upd[nt]);
        }
      #pragma unroll
      for (int nt=0;nt<4;nt++) tr[nt] = ldpk2(T1, T2, 16*nt+nb, m0);
    }
    if (do_sq){
      short8 aP[2], bPT[4][2], bP[4][2];
      #pragma unroll
      for (int kk=0;kk<2;kk++) aP[kk] = lfrag(T3, 16*w+fr, kk*32+fc);
      #pragma unroll
      for (int nt=0;nt<4;nt++){
        #pragma unroll
        for (int kk=0;kk<2;kk++){
          bPT[nt][kk] = lfrag(T4, 16*nt+fr, kk*32+fc);
          bP[nt][kk]  = lfrag(T3, 16*nt+fr, kk*32+fc);
        }
        c1[nt] = (f32x4){0.f,0.f,0.f,0.f};
        c2[nt] = (f32x4){0.f,0.f,0.f,0.f};
      }
      #pragma unroll
      for (int nt=0;nt<4;nt++)
        #pragma unroll
        for (int kk=0;kk<2;kk++){
          c1[nt] = MM(aP[kk],  bPT[nt][kk], c1[nt]);   // N^2p
          c2[nt] = MM(aPT[kk], bP[nt][kk],  c2[nt]);   // (N^2p)^T
        }
    }
    __syncthreads();
    if (do_upd){
      #pragma unroll
      for (int nt=0;nt<4;nt++){
        int n = 16*nt + nb;
        stpk_hl(T1, T2, n, m0, tr[nt].x+upd[nt][0], tr[nt].y+upd[nt][1],
                               tr[nt].z+upd[nt][2], tr[nt].w+upd[nt][3]);
      }
    }
    if (do_sq){
      #pragma unroll
      for (int nt=0;nt<4;nt++){
        int n = 16*nt + nb;
        stpk(T4, n, m0, c1[nt][0],c1[nt][1],c1[nt][2],c1[nt][3]);  // PT_new
        stpk(T3, n, m0, c2[nt][0],c2[nt][1],c2[nt][2],c2[nt][3]);  // P_new
      }
    }
    __syncthreads();
  }

  // ---- C1: MFMA transposes KnT->T3, VT->T4 (identity B-frags; no LDS reads)
  {
    short8 aKg[2], aVg[2];
    #pragma unroll
    for (int kk=0;kk<2;kk++){
      aKg[kk] = gfrag(Kg, 16*w+fr, kk*32+fc);
      aVg[kk] = gfrag(Vg, 16*w+fr, kk*32+fc);
    }
    #pragma unroll
    for (int nt=0;nt<4;nt++){
      f32x4 ck = (f32x4){0.f,0.f,0.f,0.f};
      f32x4 cv = (f32x4){0.f,0.f,0.f,0.f};
      int row = 16*nt + nb;
      #pragma unroll
      for (int kk=0;kk<2;kk++){
        short8 bi;
        int col0 = kk*32 + fc;
        #pragma unroll
        for (int e=0;e<8;e++) bi[e] = (col0+e == 16*nt+fr) ? (short)0x3F80 : (short)0;
        ck = MM(aKg[kk], bi, ck);
        cv = MM(aVg[kk], bi, cv);
      }
      stpk(T3, row, m0, ck[0],ck[1],ck[2],ck[3]);
      stpk(T4, row, m0, cv[0],cv[1],cv[2],cv[3]);
    }
  }
  __syncthreads();

  // ---- C2: WVT = (T*V)^T -> T5 ; WKnT = (T*Kn)^T -> T4
  {
    short8 a1[2], a2[2];
    #pragma unroll
    for (int kk=0;kk<2;kk++){
      a1[kk] = lfrag(T1, 16*w+fr, kk*32+fc);
      a2[kk] = lfrag(T2, 16*w+fr, kk*32+fc);
    }
    f32x4 cwv[4], cwk[4];
    #pragma unroll
    for (int nt=0;nt<4;nt++){ cwv[nt]=(f32x4){0.f,0.f,0.f,0.f}; cwk[nt]=(f32x4){0.f,0.f,0.f,0.f}; }
    #pragma unroll
    for (int nt=0;nt<4;nt++)
      #pragma unroll
      for (int kk=0;kk<2;kk++){
        short8 bV = lfrag(T4, 16*nt+fr, kk*32+fc);
        cwv[nt] = MM(a1[kk], bV, cwv[nt]);
        cwv[nt] = MM(a2[kk], bV, cwv[nt]);
      }
    #pragma unroll
    for (int nt=0;nt<4;nt++)
      #pragma unroll
      for (int kk=0;kk<2;kk++){
        short8 bK = lfrag(T3, 16*nt+fr, kk*32+fc);
        cwk[nt] = MM(a1[kk], bK, cwk[nt]);
        cwk[nt] = MM(a2[kk], bK, cwk[nt]);
      }
    __syncthreads();
    #pragma unroll
    for (int nt=0;nt<4;nt++){
      int n = 16*nt + nb;
      stpk(T5, n, m0, cwv[nt][0],cwv[nt][1],cwv[nt][2],cwv[nt][3]);
      stpk(T4, n, m0, cwk[nt][0],cwk[nt][1],cwk[nt][2],cwk[nt][3]);
    }
  }
  __syncthreads();

  // ---- C3: Bc -> T5, WKn -> T3, AcT(hi/lo) -> T1/T2 ; bounce WVT(T5) to global
  {
    int row = t>>2, seg = (t&3)*16;
    size_t go = cb + (size_t)row*64 + seg;
    *(short8*)(WVTg+go)   = *(const short8*)(T5 + adr(row,seg));
    *(short8*)(WVTg+go+8) = *(const short8*)(T5 + adr(row,seg+8));

    short8 aK2[2], aWKT[2];
    #pragma unroll
    for (int kk=0;kk<2;kk++){
      aK2[kk]  = lfrag(T3, 16*w+fr, kk*32+fc);
      aWKT[kk] = lfrag(T4, 16*w+fr, kk*32+fc);
    }
    f32x4 cBc[4], cWK[4], cAc[4];
    #pragma unroll
    for (int nt=0;nt<4;nt++){ cBc[nt]=(f32x4){0.f,0.f,0.f,0.f}; cWK[nt]=(f32x4){0.f,0.f,0.f,0.f}; cAc[nt]=(f32x4){0.f,0.f,0.f,0.f}; }
    #pragma unroll
    for (int nt=0;nt<4;nt++)
      #pragma unroll
      for (int kk=0;kk<2;kk++){
        short8 bWVT = lfrag(T5, 16*nt+fr, kk*32+fc);
        cBc[nt] = MM(aK2[kk], bWVT, cBc[nt]);
      }
    #pragma unroll
    for (int nt=0;nt<4;nt++)
      #pragma unroll
      for (int kk=0;kk<2;kk++){
        short8 b1 = lfrag(T1, 16*nt+fr, kk*32+fc);
        short8 b2 = lfrag(T2, 16*nt+fr, kk*32+fc);
        cWK[nt] = MM(aK2[kk], b1, cWK[nt]);
        cWK[nt] = MM(aK2[kk], b2, cWK[nt]);
      }
    #pragma unroll
    for (int nt=0;nt<4;nt++)
      #pragma unroll
      for (int kk=0;kk<2;kk++){
        short8 bK3 = lfrag(T3, 16*nt+fr, kk*32+fc);
        cAc[nt] = MM(aWKT[kk], bK3, cAc[nt]);
      }
    __syncthreads();
    #pragma unroll
    for (int nt=0;nt<4;nt++){
      int n = 16*nt + nb;
      stpk(T5, n, m0, lr*cBc[nt][0], lr*cBc[nt][1], lr*cBc[nt][2], lr*cBc[nt][3]);
      stpk(T3, n, m0, cWK[nt][0],cWK[nt][1],cWK[nt][2],cWK[nt][3]);
      float av[4];
      #pragma unroll
      for (int r=0;r<4;r++) av[r] = ((n==m0+r)?1.f:0.f) - beta*cAc[nt][r];
      stpk_hl(T1, T2, n, m0, av[0],av[1],av[2],av[3]);
    }
  }
  __syncthreads();

  // ---- C4: coalesced bounces to global
  {
    int row = t>>2, seg = (t&3)*16;
    size_t go = cb + (size_t)row*64 + seg;
    *(short8*)(AcThi+go)   = *(const short8*)(T1 + adr(row,seg));
    *(short8*)(AcThi+go+8) = *(const short8*)(T1 + adr(row,seg+8));
    *(short8*)(AcTlo+go)   = *(const short8*)(T2 + adr(row,seg));
    *(short8*)(AcTlo+go+8) = *(const short8*)(T2 + adr(row,seg+8));
    *(short8*)(Bcb+go)     = *(const short8*)(T5 + adr(row,seg));
    *(short8*)(Bcb+go+8)   = *(const short8*)(T5 + adr(row,seg+8));
    *(short8*)(WKng+go)    = *(const short8*)(T3 + adr(row,seg));
    *(short8*)(WKng+go+8)  = *(const short8*)(T3 + adr(row,seg+8));
  }
}

// ---------------- seq v2 (fused with G2 gemm): M <- M*Ac + Bc, all-packed ----------------
// Operand swap: C' = TILE(A=AcT rows, B=M rows) => C'[j][d] = M_new[d][j] (transposed frag),
// so the packed C^T store lands in STANDARD M[d][k] layout: all LDS + global writes packed.
// Blocks >= BH run the independent G2 = x@Wg^T GEMM (MODE4, bf16) on otherwise-idle CUs.
__global__ __launch_bounds__(256) void seq_kernel(
    const bf16* __restrict__ AcThi, const bf16* __restrict__ AcTlo,
    const bf16* __restrict__ Bcb,
    bf16* __restrict__ Mpref, bf16* __restrict__ Mplo, float* __restrict__ Mout,
    const bf16* __restrict__ xb, const bf16* __restrict__ Wgb, bf16* __restrict__ G2b)
{
  __shared__ __align__(16) char smem[49152];
  if (blockIdx.x >= BH){
    int bidx = blockIdx.x - BH;
    gemm_core<4>(xb, 768, 768, nullptr, 0, 0, 0, Wgb, 768, 768,
                 nullptr, nullptr, nullptr, nullptr, G2b, 768,
                 bidx & 63, bidx >> 6, 0, smem);
    return;
  }
  char* sH0 = smem;           char* sH1 = smem + 8192;
  char* sL0 = smem + 16384;   char* sL1 = smem + 24576;
  const int bh = blockIdx.x;
  const int t = threadIdx.x, w = t>>6, L = t&63;
  const size_t cbase = (size_t)bh*NCH*4096;
  const int fr = L&15, fc = (L>>4)*8;
  const int m0 = 16*w + (L>>4)*4;   // j (col of M) slice
  const int nb = L&15;

  { float4 z = {0.f,0.f,0.f,0.f};
    ((float4*)sH0)[t] = z; ((float4*)sH0)[t+256] = z;
    ((float4*)sL0)[t] = z; ((float4*)sL0)[t+256] = z;
    short8 zs = {0,0,0,0,0,0,0,0};
    ((short8*)(Mpref + cbase))[t] = zs; ((short8*)(Mpref + cbase))[t+256] = zs;
    ((short8*)(Mplo  + cbase))[t] = zs; ((short8*)(Mplo  + cbase))[t+256] = zs;
  }

  short8 Xh[2], Xl[2]; s16x4 Xc[4];
  short8 Yh[2], Yl[2]; s16x4 Yc[4];

  auto loadf = [&](short8 (&fh)[2], short8 (&fl)[2], s16x4 (&fbc)[4], int c){
    size_t cb = cbase + (size_t)c*4096;
    #pragma unroll
    for (int kk=0;kk<2;kk++){
      size_t o = cb + (size_t)(16*w + fr)*64 + kk*32 + fc;   // AcT row j
      fh[kk] = *(const short8*)(AcThi + o);
      fl[kk] = *(const short8*)(AcTlo + o);
    }
    #pragma unroll
    for (int nt=0;nt<4;nt++)
      fbc[nt] = *(const s16x4*)(Bcb + cb + (size_t)(16*nt + nb)*64 + m0);
  };
  auto step = [&](short8 (&Ah)[2], short8 (&Al)[2], s16x4 (&Bc4)[4], int c,
                  char* rh, char* rl, char* wh, char* wl){
    __syncthreads();   // previous step's LDS writes visible
    short8 bMh[4][2], bMl[4][2];
    #pragma unroll
    for (int nt=0;nt<4;nt++)
      #pragma unroll
      for (int kk=0;kk<2;kk++){
        bMh[nt][kk] = lfrag(rh, 16*nt+fr, kk*32+fc);
        bMl[nt][kk] = lfrag(rl, 16*nt+fr, kk*32+fc);
      }
    #pragma unroll
    for (int nt=0;nt<4;nt++){
      f32x4 acc = { us2f((unsigned short)Bc4[nt][0]), us2f((unsigned short)Bc4[nt][1]),
                    us2f((unsigned short)Bc4[nt][2]), us2f((unsigned short)Bc4[nt][3]) };
      acc = MM(Ah[0], bMh[nt][0], acc);
      acc = MM(Ah[1], bMh[nt][1], acc);
      acc = MM(Ah[0], bMl[nt][0], acc);
      acc = MM(Ah[1], bMl[nt][1], acc);
      acc = MM(Al[0], bMh[nt][0], acc);
      acc = MM(Al[1], bMh[nt][1], acc);
      int d = 16*nt + nb;
      float h[4], lo[4];
      #pragma unroll
      for (int r=0;r<4;r++){ h[r] = bf2f(__float2bfloat16(acc[r])); lo[r] = acc[r]-h[r]; }
      stpk(wh, d, m0, h[0],h[1],h[2],h[3]);
      stpk(wl, d, m0, lo[0],lo[1],lo[2],lo[3]);
      if (c < NCH-1){
        size_t go = cbase + (size_t)(c+1)*4096 + (size_t)d*64 + m0;
        s16x4 ph = { f2s(h[0]), f2s(h[1]), f2s(h[2]), f2s(h[3]) };
        s16x4 pl = { f2s(lo[0]), f2s(lo[1]), f2s(lo[2]), f2s(lo[3]) };
        *(s16x4*)(Mpref + go) = ph;
        *(s16x4*)(Mplo  + go) = pl;
      } else {
        float4 fv = { acc[0], acc[1], acc[2], acc[3] };
        *(float4*)(Mout + ((size_t)bh*64 + d)*64 + m0) = fv;
      }
    }
  };

  loadf(Xh,Xl,Xc,0);
  for (int c=0; c<NCH; c+=2){
    if (c+1 < NCH) loadf(Yh,Yl,Yc,c+1);
    step(Xh,Xl,Xc,c,   sH0,sL0, sH1,sL1);
    if (c+2 < NCH) loadf(Xh,Xl,Xc,c+2);
    step(Yh,Yl,Yc,c+1, sH1,sL1, sH0,sL0);
  }
}

// ---------------- parallel output phase (unchanged from R7) ----------------
__global__ __launch_bounds__(256) void outphase_kernel(
    const bf16* __restrict__ kvqb, const bf16* __restrict__ Mpref, const bf16* __restrict__ Mplo,
    const bf16* __restrict__ WKng, const bf16* __restrict__ WVTb,
    const float* __restrict__ lr_scale, bf16* __restrict__ attn)
{
  __shared__ __align__(16) char sUT[8192];
  __shared__ __align__(16) char sAT[8192];
  const int c = blockIdx.x, bh = blockIdx.y;
  const int b = bh / H_, h = bh % H_;
  const int t = threadIdx.x, w = t>>6, L = t&63;
  const size_t PS = (size_t)B_*H_*S_*HD_;
  const size_t cb = ((size_t)bh*NCH + c)*4096;
  const size_t base_k = (size_t)bh*S_*HD_ + (size_t)c*CH*HD_;
  const bf16* Kg = kvqb + base_k;
  const bf16* Qg = kvqb + 2*PS + base_k;
  const float lr = 0.2f/(1.f + __expf(-lr_scale[h]));
  const float beta = 1.f + lr;
  const int fr = L&15, fc = (L>>4)*8;
  const int m0 = 16*w + (L>>4)*4;
  const int nb = L&15;

  {
    short8 aKn[2];
    #pragma unroll
    for (int kk=0;kk<2;kk++) aKn[kk] = gfrag(Kg, 16*w+fr, kk*32+fc);
    #pragma unroll
    for (int nt=0;nt<4;nt++){
      f32x4 cat = (f32x4){0.f,0.f,0.f,0.f};
      #pragma unroll
      for (int kk=0;kk<2;kk++) cat = MM(aKn[kk], gfrag(Qg, 16*nt+fr, kk*32+fc), cat);
      int n = 16*nt + nb;
      float v[4];
      #pragma unroll
      for (int r=0;r<4;r++) v[r] = (m0+r < n)? cat[r] : 0.f;
      stpk(sAT, n, m0, v[0],v[1],v[2],v[3]);
    }
  }

  short8 mbh[4][2], mbl[4][2], qa[2], wa[2];
  #pragma unroll
  for (int kk=0;kk<2;kk++){
    qa[kk] = gfrag(Qg, 16*w+fr, kk*32+fc);
    wa[kk] = *(const short8*)(WKng + cb + (size_t)(16*w + fr)*64 + kk*32 + fc);
  }
  #pragma unroll
  for (int nt=0;nt<4;nt++)
    #pragma unroll
    for (int kk=0;kk<2;kk++){
      size_t o = cb + (size_t)(16*nt + fr)*64 + kk*32 + fc;
      mbh[nt][kk] = *(const short8*)(Mpref + o);
      mbl[nt][kk] = *(const short8*)(Mplo  + o);
    }
  f32x4 aout[4], ap[4];
  #pragma unroll
  for (int nt=0;nt<4;nt++){ aout[nt]=(f32x4){0.f,0.f,0.f,0.f}; ap[nt]=(f32x4){0.f,0.f,0.f,0.f}; }
  #pragma unroll
  for (int nt=0;nt<4;nt++)
    #pragma unroll
    for (int kk=0;kk<2;kk++){
      aout[nt] = MM(qa[kk], mbh[nt][kk], aout[nt]);
      aout[nt] = MM(qa[kk], mbl[nt][kk], aout[nt]);
      ap[nt]   = MM(wa[kk], mbh[nt][kk], ap[nt]);
      ap[nt]   = MM(wa[kk], mbl[nt][kk], ap[nt]);
    }
  #pragma unroll
  for (int nt=0;nt<4;nt++){
    s16x4 wv4 = *(const s16x4*)(WVTb + cb + (size_t)(nt*16 + (L&15))*64 + 16*w + (L>>4)*4);
    short us[4];
    #pragma unroll
    for (int r=0;r<4;r++){
      float wv = us2f((unsigned short)wv4[r]);
      us[r] = f2s(lr*wv - beta*ap[nt][r]);
    }
    int d = nt*16 + (L&15);
    int i0 = 16*w + (L>>4)*4;
    s16x4 pk = { us[0], us[1], us[2], us[3] };
    *(s16x4*)(sUT + adr(d, i0)) = pk;
  }
  __syncthreads();
  short8 ta[2], ub[4][2];
  #pragma unroll
  for (int kk=0;kk<2;kk++)
    ta[kk] = lfrag(sAT, 16*w+fr, kk*32+fc);
  #pragma unroll
  for (int nt=0;nt<4;nt++)
    #pragma unroll
    for (int kk=0;kk<2;kk++)
      ub[nt][kk] = lfrag(sUT, 16*nt + fr, kk*32 + fc);
  #pragma unroll
  for (int nt=0;nt<4;nt++)
    #pragma unroll
    for (int kk=0;kk<2;kk++)
      aout[nt] = MM(ta[kk], ub[nt][kk], aout[nt]);
  #pragma unroll
  for (int nt=0;nt<4;nt++)
    #pragma unroll
    for (int r=0;r<4;r++)
      attn[((size_t)b*S_ + (size_t)c*CH + 16*w + (L>>4)*4 + r)*P_ + h*HD_ + nt*16 + (L&15)]
        = __float2bfloat16(aout[nt][r]);
}

extern "C" void kernel_launch(void* const* d_in, const int* in_sizes, int n_in,
                              void* d_out, int out_size, void* d_ws, size_t ws_size,
                              hipStream_t stream)
{
  const float* x     = (const float*)d_in[0];
  const float* ln_g  = (const float*)d_in[1];
  const float* ln_b  = (const float*)d_in[2];
  const float* Wk    = (const float*)d_in[3];
  const float* Wv    = (const float*)d_in[4];
  const float* Wq    = (const float*)d_in[5];
  const float* km_w1 = (const float*)d_in[6];  const float* km_b1 = (const float*)d_in[7];
  const float* km_w2 = (const float*)d_in[8];  const float* km_b2 = (const float*)d_in[9];
  const float* vm_w1 = (const float*)d_in[10]; const float* vm_b1 = (const float*)d_in[11];
  const float* vm_w2 = (const float*)d_in[12]; const float* vm_b2 = (const float*)d_in[13];
  const float* qm_w1 = (const float*)d_in[14]; const float* qm_b1 = (const float*)d_in[15];
  const float* qm_w2 = (const float*)d_in[16]; const float* qm_b2 = (const float*)d_in[17];
  const float* lnk_g = (const float*)d_in[18]; const float* lnk_b = (const float*)d_in[19];
  const float* lnv_g = (const float*)d_in[20]; const float* lnv_b = (const float*)d_in[21];
  const float* lnq_g = (const float*)d_in[22]; const float* lnq_b = (const float*)d_in[23];
  const float* Wo    = (const float*)d_in[24];
  const float* lr_sc = (const float*)d_in[25];
  const float* Wg    = (const float*)d_in[26];
  const float* bg    = (const float*)d_in[27];

  const size_t CHB = (size_t)BH*NCH*4096;

  char* ws = (char*)d_ws;
  size_t o = 0;
  bf16* xnb   = (bf16*)(ws + o); o += (size_t)M_*D_*2;   // later reused as bf16 G2
  bf16* xb    = (bf16*)(ws + o); o += (size_t)M_*D_*2;
  bf16* Hb    = (bf16*)(ws + o); o += (size_t)M_*576*2;
  bf16* kvqb  = (bf16*)(ws + o); o += (size_t)3*M_*P_*2;
  bf16* attn  = (bf16*)(ws + o); o += (size_t)M_*P_*2;
  bf16* AcThi = (bf16*)(ws + o); o += CHB*2;
  bf16* AcTlo = (bf16*)(ws + o); o += CHB*2;
  bf16* Bcb   = (bf16*)(ws + o); o += CHB*2;
  bf16* WVTb  = (bf16*)(ws + o); o += CHB*2;
  bf16* WKng  = (bf16*)(ws + o); o += CHB*2;
  bf16* Mpref = (bf16*)(ws + o); o += CHB*2;
  bf16* Mplo  = (bf16*)(ws + o); o += CHB*2;
  bf16* Whb   = (bf16*)(ws + o); o += (size_t)640*768*2;
  bf16* Wkvqb = (bf16*)(ws + o); o += (size_t)2304*960*2;
  bf16* Wob   = (bf16*)(ws + o); o += (size_t)768*768*2;
  bf16* Wgb   = (bf16*)(ws + o); o += (size_t)768*768*2;
  float* biasb= (float*)(ws + o); o += 3264*4;
  bf16* G2b   = xnb;   // xnb dead after gemm<1>

  float* outF = (float*)d_out;
  float* Mout = outF + (size_t)M_*D_;

  pack_ln_kernel<<<15181 + M_, 256, 0, stream>>>(
      km_w1, vm_w1, qm_w1, Wk, Wv, Wq, km_w2, vm_w2, qm_w2, Wo, Wg,
      km_b1, vm_b1, qm_b1, km_b2, vm_b2, qm_b2,
      lnk_g, lnv_g, lnq_g, lnk_b, lnv_b, lnq_b,
      Whb, Wkvqb, Wob, Wgb, biasb,
      x, ln_g, ln_b, xnb, xb);

  gemm_kernel<0><<<dim3(64,5,1), 256, 0, stream>>>(xnb, 768, 768, nullptr, 0, 0, 0,
                                                   Whb, 768, 640, biasb, nullptr, nullptr, nullptr, Hb, 576);
  gemm_kernel<1><<<dim3(64,6,3), 256, 0, stream>>>(xnb, 768, 768, Hb, 576, 192, 192,
                                                   Wkvqb, 960, 768, biasb + 576, nullptr,
                                                   biasb + 2880, biasb + 3072, kvqb, 768);

  prep_kernel<<<dim3(NCH, BH), 256, 0, stream>>>(kvqb, lr_sc, WKng, WVTb, AcThi, AcTlo, Bcb);

  // fused: blocks 0..47 = chunk recurrence; blocks 48..431 = G2 = x@Wg^T (bf16 -> G2b)
  seq_kernel<<<BH + 384, 256, 0, stream>>>(AcThi, AcTlo, Bcb, Mpref, Mplo, Mout,
                                           xb, Wgb, G2b);

  outphase_kernel<<<dim3(NCH, BH), 256, 0, stream>>>(kvqb, Mpref, Mplo, WKng, WVTb, lr_sc, attn);

  // out = (attn @ Wo^T) * sigmoid(G2 + bg)
  gemm_kernel<3><<<dim3(64,6,1), 256, 0, stream>>>(attn, 768, 768, nullptr, 0, 0, 0,
                                                   Wob, 768, 768, bg, G2b, nullptr, nullptr, outF, 768);
}